// Round 10
// baseline (1924.805 us; speedup 1.0000x reference)
//
#include <hip/hip_runtime.h>
#include <math.h>

#define B_SZ 16
#define L_SZ 1024
#define NMAT (B_SZ * L_SZ)   // 16384
#define DIMV 136
#define QKVD 408
#define HD 34
#define NH 4
#define NSWEEP 5

typedef __attribute__((ext_vector_type(8))) short short8;
typedef __attribute__((ext_vector_type(16))) float f32x16;
union F8 { short8 s; uint32_t u[4]; };

struct S3 { uint32_t h, m, l; };
// 3-way truncation split of f32 into bf16 parts (stored as f32 with low16=0).
__device__ __forceinline__ S3 split3(float x) {
  S3 r;
  uint32_t xb = __float_as_uint(x);
  r.h = xb & 0xffff0000u;
  float rr = x - __uint_as_float(r.h);
  r.m = __float_as_uint(rr) & 0xffff0000u;
  float r2 = rr - __uint_as_float(r.m);
  r.l = __float_as_uint(r2) & 0xffff0000u;
  return r;
}
__device__ __forceinline__ uint32_t pkb(uint32_t a, uint32_t b) { return (a >> 16) | b; }

// ---------------------------------------------------------------------------
// sel16: extract a[j] for runtime j via cndmask tree
// ---------------------------------------------------------------------------
__device__ __forceinline__ float sel16(const float a[16], int j) {
  float p0 = (j & 1) ? a[1] : a[0];
  float p1 = (j & 1) ? a[3] : a[2];
  float p2 = (j & 1) ? a[5] : a[4];
  float p3 = (j & 1) ? a[7] : a[6];
  float p4 = (j & 1) ? a[9] : a[8];
  float p5 = (j & 1) ? a[11] : a[10];
  float p6 = (j & 1) ? a[13] : a[12];
  float p7 = (j & 1) ? a[15] : a[14];
  float q0 = (j & 2) ? p1 : p0;
  float q1 = (j & 2) ? p3 : p2;
  float q2 = (j & 2) ? p5 : p4;
  float q3 = (j & 2) ? p7 : p6;
  float r0 = (j & 4) ? q1 : q0;
  float r1 = (j & 4) ? q3 : q2;
  return (j & 8) ? r1 : r0;
}

// ---------------------------------------------------------------------------
// Register+shuffle parallel cyclic Jacobi, 16x16 per 16-lane group.
// A: lane sub owns COLUMN sub; V: lane sub owns ROW sub (V'=V·G is in-lane,
// zero V shuffles). DS ops/round: 16 (a-cols) + 1 (diag) + 1 (apq) + 8 (t)
// = 26. sched_barrier(0) per round stops the compiler from software-
// pipelining the unrolled rounds (R9: live-range blowup -> 212 VGPR).
// ---------------------------------------------------------------------------
__device__ __forceinline__ void jacobi16_rv(float a[16], float v[16], float& diag,
                                            const int lane) {
  const int sub = lane & 15;
  const int gbase = lane & 48;
  for (int sweep = 0; sweep < NSWEEP; ++sweep) {
#pragma unroll
    for (int r = 0; r < 15; ++r) {
      int partner;
      if (sub == 15) partner = r;
      else {
        int d = sub - r; if (d < 0) d += 15;
        if (d == 0) partner = 15;
        else if (d <= 7) { partner = r - d; if (partner < 0) partner += 15; }
        else { partner = r + 15 - d; if (partner >= 15) partner -= 15; }
      }
      const int plane = gbase | partner;
      const bool amP = sub < partner;
      const int pl = gbase | (amP ? sub : partner);

      float oa[16];
#pragma unroll
      for (int i = 0; i < 16; ++i) oa[i] = __shfl(a[i], plane);
      const float diag_o = __shfl(diag, plane);
      const float apq = __shfl(sel16(a, partner), pl);
      const float app = amP ? diag : diag_o;
      const float aqq = amP ? diag_o : diag;

      float t, c, s;
      {
        float th = (aqq - app) / (2.f * apq);
        float tt = 1.f / (fabsf(th) + sqrtf(fmaf(th, th, 1.f)));
        tt = (th < 0.f) ? -tt : tt;
        t = (fabsf(apq) < 1e-30f) ? 0.f : tt;
        c = rsqrtf(fmaf(t, t, 1.f));
        s = t * c;
      }
      const float sgn = amP ? -s : s;
      // ---- A column mix (own column vs partner column) ----
#pragma unroll
      for (int i = 0; i < 16; ++i) a[i] = fmaf(sgn, oa[i], c * a[i]);
      // ---- diagonal via closed-form 2-sided rotation ----
      {
        const float cc = c * c, ss = s * s, cs2 = 2.f * c * s;
        diag = amP ? fmaf(cc, app, fmaf(ss, aqq, -cs2 * apq))
                   : fmaf(ss, app, fmaf(cc, aqq,  cs2 * apq));
      }
      // ---- row mix (A) + column rotation (V, row-stored => in-lane) ----
#pragma unroll
      for (int k = 0; k < 8; ++k) {
        const int owner = (k == 0) ? r : (r + k) % 15;
        const float tk = __shfl(t, gbase | owner);
        const float ck = rsqrtf(fmaf(tk, tk, 1.f));
        const float sk = tk * ck;
        int pk, qk;
        if (k == 0) { pk = r; qk = 15; }
        else {
          const int u = (r + k) % 15, w = (r + 15 - k) % 15;
          pk = u < w ? u : w; qk = u < w ? w : u;
        }
        float tp = a[pk], tq = a[qk];
        a[pk] = fmaf(-sk, tq, ck * tp);
        a[qk] = fmaf( sk, tp, ck * tq);
        tp = v[pk]; tq = v[qk];
        v[pk] = fmaf(-sk, tq, ck * tp);
        v[qk] = fmaf( sk, tp, ck * tq);
      }
      // pin round boundary: no cross-round scheduling (VGPR control)
      __builtin_amdgcn_sched_barrier(0);
    }
  }
}

// ---------------------------------------------------------------------------
// K1: log_eig(S) -> tril vector, DIM-MAJOR out: vec[136][16384]
// ---------------------------------------------------------------------------
__global__ __launch_bounds__(256, 4) void k1_logvec(const float* __restrict__ S, float* __restrict__ vec) {
  __shared__ float Vld[16][272];   // V row-major: Vld[m][row*17 + col]
  __shared__ float lwld[16][16];
  const int tid = threadIdx.x;
  const int lane = tid & 63;
  const int mloc = tid >> 4;
  const int sub = tid & 15;
  const int mat = blockIdx.x * 16 + mloc;
  float a[16], v[16], diag = 0.f;
  const float* Sp = S + (size_t)mat * 256;
#pragma unroll
  for (int i = 0; i < 16; ++i) {
    a[i] = Sp[i * 16 + sub];
    v[i] = (i == sub) ? 1.f : 0.f;
    if (i == sub) diag = a[i];
  }
  jacobi16_rv(a, v, diag, lane);
  float* Vc = &Vld[mloc][0];
#pragma unroll
  for (int j = 0; j < 16; ++j) Vc[sub * 17 + j] = v[j];   // row sub
  lwld[mloc][sub] = __logf(fmaxf(diag, 1e-8f));
  __syncthreads();
  // logS_{r,c} = sum_j lw_j V[r][j] V[c][j]
  for (int idx = sub; idx < DIMV; idx += 16) {
    int rr = (int)((sqrtf(8.f * (float)idx + 1.f) - 1.f) * 0.5f);
    while ((rr + 1) * (rr + 2) / 2 <= idx) ++rr;
    while (rr * (rr + 1) / 2 > idx) --rr;
    const int ccol = idx - rr * (rr + 1) / 2;
    float acc = 0.f;
#pragma unroll
    for (int j = 0; j < 16; ++j)
      acc += lwld[mloc][j] * Vc[rr * 17 + j] * Vc[ccol * 17 + j];
    vec[(size_t)idx * NMAT + mat] = acc;
  }
}

// ---------------------------------------------------------------------------
// K2: QKV projection. X dim-major [136][16384] (coalesced float2 loads, 2
// rows/thread); W wave-uniform; out qkv [part][b*4+h][34][1024].
// ---------------------------------------------------------------------------
__global__ __launch_bounds__(256) void k2_qkv(const float* __restrict__ X, const float* __restrict__ W,
                                              const float* __restrict__ bias, float* __restrict__ Y) {
  const int r0 = blockIdx.x * 512 + threadIdx.x * 2;
  const int n0 = blockIdx.y * 17;
  float accx[17], accy[17];
#pragma unroll
  for (int c = 0; c < 17; ++c) { const float bv = bias[n0 + c]; accx[c] = bv; accy[c] = bv; }
  for (int k = 0; k < DIMV; ++k) {
    const float2 xv = *(const float2*)&X[(size_t)k * NMAT + r0];
#pragma unroll
    for (int c = 0; c < 17; ++c) {
      const float wv = W[(size_t)(n0 + c) * DIMV + k];
      accx[c] = fmaf(wv, xv.x, accx[c]);
      accy[c] = fmaf(wv, xv.y, accy[c]);
    }
  }
  const int b = r0 >> 10, lrow = r0 & 1023;
#pragma unroll
  for (int c = 0; c < 17; ++c) {
    const int n = n0 + c;
    const int p = n / DIMV, rr = n - p * DIMV;
    const int hh = rr / HD, dd = rr - hh * HD;
    *(float2*)&Y[(((size_t)(p * 64 + b * NH + hh)) * HD + dd) * L_SZ + lrow] =
        make_float2(accx[c], accy[c]);
  }
}

// ---------------------------------------------------------------------------
// K3: flash attention via split-bf16x3 MFMA (32x32x16).
// QKV dim-major [part][bh][dim][row]; output attn DIM-MAJOR [136][16384].
// ---------------------------------------------------------------------------
__global__ __launch_bounds__(256) void k3_attn(const float* __restrict__ QKV, float* __restrict__ Oout) {
  __shared__ __align__(16) uint32_t Kh[6 * 32 * 4], Km[6 * 32 * 4], Kl[6 * 32 * 4];
  __shared__ __align__(16) uint16_t VTh[4 * 64 * 8], VTm[4 * 64 * 8], VTl[4 * 64 * 8];
  const int tid = threadIdx.x;
  const int lane = tid & 63;
  const int w = tid >> 6;
  const int bh = blockIdx.x;
  const int head = bh & 3;
  const int b = bh >> 2;
  const int qrl = lane & 31;
  const int hh = lane >> 5;
  const int row = blockIdx.y * 128 + w * 32 + qrl;
  const float* __restrict__ Qp = QKV + ((size_t)(0 * 64 + bh)) * HD * L_SZ;
  const float* __restrict__ Kp = QKV + ((size_t)(1 * 64 + bh)) * HD * L_SZ;
  const float* __restrict__ Vp = QKV + ((size_t)(2 * 64 + bh)) * HD * L_SZ;
  const float scale = 0.1714985851425088f;  // 1/sqrt(34)

  for (int i = tid; i < 6 * 32 * 4; i += 256) { Kh[i] = 0; Km[i] = 0; Kl[i] = 0; }
  for (int i = tid; i < 4 * 64 * 8; i += 256) { VTh[i] = 0; VTm[i] = 0; VTl[i] = 0; }

  F8 qfh[3], qfm[3], qfl[3];
#pragma unroll
  for (int c = 0; c < 3; ++c) {
#pragma unroll
    for (int e2 = 0; e2 < 4; ++e2) {
      const int kd = c * 16 + hh * 8 + 2 * e2;
      float x = 0.f, y = 0.f;
      if (kd < HD) {
        x = Qp[(size_t)kd * L_SZ + row] * scale;
        y = Qp[(size_t)(kd + 1) * L_SZ + row] * scale;
      }
      S3 sx = split3(x), sy = split3(y);
      qfh[c].u[e2] = pkb(sx.h, sy.h);
      qfm[c].u[e2] = pkb(sx.m, sy.m);
      qfl[c].u[e2] = pkb(sx.l, sy.l);
    }
  }

  f32x16 o0, o1;
#pragma unroll
  for (int i = 0; i < 16; ++i) { o0[i] = 0.f; o1[i] = 0.f; }
  float mrun = -3.0e38f, lsum = 0.f;

  for (int t = 0; t < 32; ++t) {
    __syncthreads();
    for (int u = tid; u < 1088; u += 256) {
      const bool isK = u < 544;
      const int e = isK ? u : u - 544;
      const int key = e & 31;
      const int j = e >> 5;
      const float* __restrict__ P = isK ? Kp : Vp;
      const size_t base = (size_t)(t * 32 + key);
      const float x = P[(size_t)(2 * j) * L_SZ + base];
      const float y = P[(size_t)(2 * j + 1) * L_SZ + base];
      const S3 sx = split3(x), sy = split3(y);
      if (isK) {
        const int di = ((j >> 2) * 32 + key) * 4 + (j & 3);
        Kh[di] = pkb(sx.h, sy.h); Km[di] = pkb(sx.m, sy.m); Kl[di] = pkb(sx.l, sy.l);
      } else {
        const int b0 = ((key >> 3) * 64 + 2 * j) * 8 + (key & 7);
        VTh[b0] = (uint16_t)(sx.h >> 16); VTm[b0] = (uint16_t)(sx.m >> 16); VTl[b0] = (uint16_t)(sx.l >> 16);
        VTh[b0 + 8] = (uint16_t)(sy.h >> 16); VTm[b0 + 8] = (uint16_t)(sy.m >> 16); VTl[b0 + 8] = (uint16_t)(sy.l >> 16);
      }
    }
    __syncthreads();

    f32x16 s;
#pragma unroll
    for (int i = 0; i < 16; ++i) s[i] = 0.f;
#pragma unroll
    for (int c = 0; c < 3; ++c) {
      F8 ah, am, al;
      const int kidx = ((c * 2 + hh) * 32 + qrl) * 4;
      ah.s = *(const short8*)&Kh[kidx];
      am.s = *(const short8*)&Km[kidx];
      al.s = *(const short8*)&Kl[kidx];
      s = __builtin_amdgcn_mfma_f32_32x32x16_bf16(ah.s, qfh[c].s, s, 0, 0, 0);
      s = __builtin_amdgcn_mfma_f32_32x32x16_bf16(ah.s, qfm[c].s, s, 0, 0, 0);
      s = __builtin_amdgcn_mfma_f32_32x32x16_bf16(am.s, qfh[c].s, s, 0, 0, 0);
      s = __builtin_amdgcn_mfma_f32_32x32x16_bf16(ah.s, qfl[c].s, s, 0, 0, 0);
      s = __builtin_amdgcn_mfma_f32_32x32x16_bf16(am.s, qfm[c].s, s, 0, 0, 0);
      s = __builtin_amdgcn_mfma_f32_32x32x16_bf16(al.s, qfh[c].s, s, 0, 0, 0);
    }

    float mymax = s[0];
#pragma unroll
    for (int e = 1; e < 16; ++e) mymax = fmaxf(mymax, s[e]);
    const float pmax = fmaxf(mymax, __shfl_xor(mymax, 32));
    const float mn = fmaxf(mrun, pmax);
    const float corr = __expf(mrun - mn);
    mrun = mn;
    float p[16]; float ps = 0.f;
#pragma unroll
    for (int e = 0; e < 16; ++e) { p[e] = __expf(s[e] - mn); ps += p[e]; }
    ps += __shfl_xor(ps, 32);
    lsum = lsum * corr + ps;
    o0 *= corr; o1 *= corr;

    uint32_t uo[3][8], po[3][8];
#pragma unroll
    for (int g = 0; g < 8; ++g) {
      const S3 s0 = split3(p[2 * g]), s1 = split3(p[2 * g + 1]);
      uo[0][g] = pkb(s0.h, s1.h); uo[1][g] = pkb(s0.m, s1.m); uo[2][g] = pkb(s0.l, s1.l);
    }
#pragma unroll
    for (int sp = 0; sp < 3; ++sp)
#pragma unroll
      for (int g = 0; g < 8; ++g) po[sp][g] = (uint32_t)__shfl_xor((int)uo[sp][g], 32);
    F8 pf[3][2];
#pragma unroll
    for (int sp = 0; sp < 3; ++sp) {
      pf[sp][0].u[0] = hh ? po[sp][2] : uo[sp][0];
      pf[sp][0].u[1] = hh ? po[sp][3] : uo[sp][1];
      pf[sp][0].u[2] = hh ? uo[sp][2] : po[sp][0];
      pf[sp][0].u[3] = hh ? uo[sp][3] : po[sp][1];
      pf[sp][1].u[0] = hh ? po[sp][6] : uo[sp][4];
      pf[sp][1].u[1] = hh ? po[sp][7] : uo[sp][5];
      pf[sp][1].u[2] = hh ? uo[sp][6] : po[sp][4];
      pf[sp][1].u[3] = hh ? uo[sp][7] : po[sp][5];
    }

#pragma unroll
    for (int dt = 0; dt < 2; ++dt) {
#pragma unroll
      for (int kc = 0; kc < 2; ++kc) {
        const int vb = ((kc * 2 + hh) * 64 + dt * 32 + qrl) * 8;
        F8 vh2, vm2, vl2;
        vh2.s = *(const short8*)&VTh[vb];
        vm2.s = *(const short8*)&VTm[vb];
        vl2.s = *(const short8*)&VTl[vb];
        f32x16 oa = dt ? o1 : o0;
        oa = __builtin_amdgcn_mfma_f32_32x32x16_bf16(vh2.s, pf[0][kc].s, oa, 0, 0, 0);
        oa = __builtin_amdgcn_mfma_f32_32x32x16_bf16(vh2.s, pf[1][kc].s, oa, 0, 0, 0);
        oa = __builtin_amdgcn_mfma_f32_32x32x16_bf16(vm2.s, pf[0][kc].s, oa, 0, 0, 0);
        oa = __builtin_amdgcn_mfma_f32_32x32x16_bf16(vh2.s, pf[2][kc].s, oa, 0, 0, 0);
        oa = __builtin_amdgcn_mfma_f32_32x32x16_bf16(vm2.s, pf[1][kc].s, oa, 0, 0, 0);
        oa = __builtin_amdgcn_mfma_f32_32x32x16_bf16(vl2.s, pf[0][kc].s, oa, 0, 0, 0);
        if (dt) o1 = oa; else o0 = oa;
      }
    }
  }

  // ---- epilogue: dim-major coalesced stores attn[head*34+d][16384] ----
  const float inv = 1.f / lsum;
  const int rowG = b * L_SZ + row;
#pragma unroll
  for (int dt = 0; dt < 2; ++dt) {
#pragma unroll
    for (int rq = 0; rq < 4; ++rq) {
#pragma unroll
      for (int j = 0; j < 4; ++j) {
        const int d = dt * 32 + 8 * rq + 4 * hh + j;
        if (d < HD) {
          const float val = (dt ? o1[rq * 4 + j] : o0[rq * 4 + j]) * inv;
          Oout[(size_t)(head * HD + d) * NMAT + rowG] = val;
        }
      }
    }
  }
}

// ---------------------------------------------------------------------------
// K4: out-projection + residual, all dim-major, 2 rows/thread, coalesced.
// ---------------------------------------------------------------------------
__global__ __launch_bounds__(256) void k4_outproj(const float* __restrict__ X, const float* __restrict__ W,
                                                  const float* __restrict__ bias, const float* __restrict__ resid,
                                                  float* __restrict__ Y) {
  const int r0 = blockIdx.x * 512 + threadIdx.x * 2;
  const int n0 = blockIdx.y * 17;
  float accx[17], accy[17];
#pragma unroll
  for (int c = 0; c < 17; ++c) { const float bv = bias[n0 + c]; accx[c] = bv; accy[c] = bv; }
  for (int k = 0; k < DIMV; ++k) {
    const float2 xv = *(const float2*)&X[(size_t)k * NMAT + r0];
#pragma unroll
    for (int c = 0; c < 17; ++c) {
      const float wv = W[(size_t)(n0 + c) * DIMV + k];
      accx[c] = fmaf(wv, xv.x, accx[c]);
      accy[c] = fmaf(wv, xv.y, accy[c]);
    }
  }
#pragma unroll
  for (int c = 0; c < 17; ++c) {
    const float2 rv = *(const float2*)&resid[(size_t)(n0 + c) * NMAT + r0];
    *(float2*)&Y[(size_t)(n0 + c) * NMAT + r0] = make_float2(accx[c] + rv.x, accy[c] + rv.y);
  }
}

// ---------------------------------------------------------------------------
// K5: rebuild symmetric matrix from vec_out (dim-major), exp_eig, write
// 16x16 output.
// ---------------------------------------------------------------------------
__global__ __launch_bounds__(256, 4) void k5_expm(const float* __restrict__ vecOut, float* __restrict__ out) {
  __shared__ float Vld[16][272];   // V row-major
  __shared__ float eld[16][16];
  const int tid = threadIdx.x;
  const int lane = tid & 63;
  const int mloc = tid >> 4;
  const int sub = tid & 15;
  const int mat = blockIdx.x * 16 + mloc;
  float a[16], v[16], diag = 0.f;
#pragma unroll
  for (int i = 0; i < 16; ++i) {
    const int rr = i > sub ? i : sub;
    const int cc = i + sub - rr;
    a[i] = vecOut[(size_t)(rr * (rr + 1) / 2 + cc) * NMAT + mat];
    v[i] = (i == sub) ? 1.f : 0.f;
    if (i == sub) diag = a[i];
  }
  jacobi16_rv(a, v, diag, lane);
  float* Vc = &Vld[mloc][0];
#pragma unroll
  for (int j = 0; j < 16; ++j) Vc[sub * 17 + j] = v[j];   // row sub
  eld[mloc][sub] = __expf(diag);
  __syncthreads();
  // O[i][j] = sum_m e_m V[i][m] V[j][m]; this thread computes column j=sub
  // using its own V row (registers) for V[sub][m].
  float u[16];
#pragma unroll
  for (int m = 0; m < 16; ++m) u[m] = eld[mloc][m] * v[m];
#pragma unroll
  for (int i = 0; i < 16; ++i) {
    float acc = 0.f;
#pragma unroll
    for (int m = 0; m < 16; ++m) acc = fmaf(u[m], Vc[i * 17 + m], acc);
    out[(size_t)mat * 256 + i * 16 + sub] = acc;
  }
}

// ---------------------------------------------------------------------------
extern "C" void kernel_launch(void* const* d_in, const int* in_sizes, int n_in,
                              void* d_out, int out_size, void* d_ws, size_t ws_size,
                              hipStream_t stream) {
  const float* S     = (const float*)d_in[0];
  const float* in_w  = (const float*)d_in[1];
  const float* in_b  = (const float*)d_in[2];
  const float* out_w = (const float*)d_in[3];
  const float* out_b = (const float*)d_in[4];
  float* out = (float*)d_out;
  float* ws = (float*)d_ws;
  // workspace (f32), activations dim-major:
  // vec_in[136][16384] | qkv[3][64][34][1024] | attn[136][16384] | vec_out[136][16384]
  float* vec_in  = ws;
  float* qkv     = vec_in + (size_t)NMAT * DIMV;
  float* attn    = qkv    + (size_t)NMAT * QKVD;
  float* vec_out = attn   + (size_t)NMAT * DIMV;

  k1_logvec <<<dim3(NMAT / 16),      dim3(256), 0, stream>>>(S, vec_in);
  k2_qkv    <<<dim3(NMAT / 512, 24), dim3(256), 0, stream>>>(vec_in, in_w, in_b, qkv);
  k3_attn   <<<dim3(64, 8),          dim3(256), 0, stream>>>(qkv, attn);
  k4_outproj<<<dim3(NMAT / 512, 8),  dim3(256), 0, stream>>>(attn, out_w, out_b, vec_in, vec_out);
  k5_expm   <<<dim3(NMAT / 16),      dim3(256), 0, stream>>>(vec_out, out);
}

// Round 11
// 636.918 us; speedup vs baseline: 3.0221x; 3.0221x over previous
//
#include <hip/hip_runtime.h>
#include <math.h>

#define B_SZ 16
#define L_SZ 1024
#define NMAT (B_SZ * L_SZ)   // 16384
#define DIMV 136
#define QKVD 408
#define HD 34
#define NH 4
#define NSWEEP 5

typedef __attribute__((ext_vector_type(8))) short short8;
typedef __attribute__((ext_vector_type(16))) float f32x16;
union F8 { short8 s; uint32_t u[4]; };

struct S3 { uint32_t h, m, l; };
// 3-way truncation split of f32 into bf16 parts (stored as f32 with low16=0).
__device__ __forceinline__ S3 split3(float x) {
  S3 r;
  uint32_t xb = __float_as_uint(x);
  r.h = xb & 0xffff0000u;
  float rr = x - __uint_as_float(r.h);
  r.m = __float_as_uint(rr) & 0xffff0000u;
  float r2 = rr - __uint_as_float(r.m);
  r.l = __float_as_uint(r2) & 0xffff0000u;
  return r;
}
__device__ __forceinline__ uint32_t pkb(uint32_t a, uint32_t b) { return (a >> 16) | b; }

// ---------------------------------------------------------------------------
// sel16: extract a[j] for runtime j via cndmask tree
// ---------------------------------------------------------------------------
__device__ __forceinline__ float sel16(const float a[16], int j) {
  float p0 = (j & 1) ? a[1] : a[0];
  float p1 = (j & 1) ? a[3] : a[2];
  float p2 = (j & 1) ? a[5] : a[4];
  float p3 = (j & 1) ? a[7] : a[6];
  float p4 = (j & 1) ? a[9] : a[8];
  float p5 = (j & 1) ? a[11] : a[10];
  float p6 = (j & 1) ? a[13] : a[12];
  float p7 = (j & 1) ? a[15] : a[14];
  float q0 = (j & 2) ? p1 : p0;
  float q1 = (j & 2) ? p3 : p2;
  float q2 = (j & 2) ? p5 : p4;
  float q3 = (j & 2) ? p7 : p6;
  float r0 = (j & 4) ? q1 : q0;
  float r1 = (j & 4) ? q3 : q2;
  return (j & 8) ? r1 : r0;
}

// ---------------------------------------------------------------------------
// Register+shuffle parallel cyclic Jacobi (16x16 per 16-lane group).
// R6-measured form (206us, VGPR 88): lane sub owns column sub of A and V.
// DS ops/round: 16 (a) + 16 (v) + 1 (diag) + 1 (apq) + 8 (t bcast) = 42;
// c,s recomputed per-lane from broadcast t (bit-identical).
// NOTE: row-major-V variant (26 DS ops) abandoned -- R9: compiler pipelines
// the unrolled rounds to 212 VGPR; R10: capping spills to scratch (2.6 GB).
// ---------------------------------------------------------------------------
__device__ __forceinline__ void jacobi16_reg(float a[16], float v[16], float& diag,
                                             const int lane) {
  const int sub = lane & 15;
  const int gbase = lane & 48;
  for (int sweep = 0; sweep < NSWEEP; ++sweep) {
#pragma unroll
    for (int r = 0; r < 15; ++r) {
      int partner;
      if (sub == 15) partner = r;
      else {
        int d = sub - r; if (d < 0) d += 15;
        if (d == 0) partner = 15;
        else if (d <= 7) { partner = r - d; if (partner < 0) partner += 15; }
        else { partner = r + 15 - d; if (partner >= 15) partner -= 15; }
      }
      const int plane = gbase | partner;
      float oa[16], ov[16];
#pragma unroll
      for (int i = 0; i < 16; ++i) oa[i] = __shfl(a[i], plane);
#pragma unroll
      for (int i = 0; i < 16; ++i) ov[i] = __shfl(v[i], plane);
      const float diag_o = __shfl(diag, plane);
      const bool amP = sub < partner;
      const float app = amP ? diag : diag_o;
      const float aqq = amP ? diag_o : diag;
      const float apq_loc = sel16(a, partner);
      const int pl = gbase | (amP ? sub : partner);
      const float apq = __shfl(apq_loc, pl);
      float c, s, t;
      {
        float theta = (aqq - app) / (2.f * apq);
        float tt = 1.f / (fabsf(theta) + sqrtf(fmaf(theta, theta, 1.f)));
        tt = (theta < 0.f) ? -tt : tt;
        t = (fabsf(apq) < 1e-30f) ? 0.f : tt;
        c = rsqrtf(fmaf(t, t, 1.f));
        s = t * c;
      }
      const float sgn = amP ? -s : s;
#pragma unroll
      for (int i = 0; i < 16; ++i) {
        a[i] = fmaf(sgn, oa[i], c * a[i]);
        v[i] = fmaf(sgn, ov[i], c * v[i]);
      }
      const float cc = c * c, ss2 = s * s, cs2 = 2.f * c * s;
      const float dp = fmaf(cc, app, fmaf(ss2, aqq, -cs2 * apq));
      const float dq = fmaf(ss2, app, fmaf(cc, aqq, cs2 * apq));
      diag = amP ? dp : dq;
#pragma unroll
      for (int k = 0; k < 8; ++k) {
        const int owner = (k == 0) ? r : (r + k) % 15;
        const float tk = __shfl(t, gbase | owner);
        const float ck = rsqrtf(fmaf(tk, tk, 1.f));
        const float sk = tk * ck;
        int pk, qk;
        if (k == 0) { pk = r; qk = 15; }
        else {
          const int u = (r + k) % 15, w = (r + 15 - k) % 15;
          pk = u < w ? u : w; qk = u < w ? w : u;
        }
        float tp = a[pk], tq = a[qk];
        a[pk] = fmaf(-sk, tq, ck * tp);
        a[qk] = fmaf(sk, tp, ck * tq);
      }
    }
  }
}

// ---------------------------------------------------------------------------
// K1: log_eig(S) -> tril vector, DIM-MAJOR out: vec[136][16384]
// ---------------------------------------------------------------------------
__global__ __launch_bounds__(256) void k1_logvec(const float* __restrict__ S, float* __restrict__ vec) {
  __shared__ float Vld[16][272];   // V column-major: Vld[m][col*17 + row]
  __shared__ float lwld[16][16];
  const int tid = threadIdx.x;
  const int lane = tid & 63;
  const int mloc = tid >> 4;
  const int sub = tid & 15;
  const int mat = blockIdx.x * 16 + mloc;
  float a[16], v[16], diag = 0.f;
  const float* Sp = S + (size_t)mat * 256;
#pragma unroll
  for (int i = 0; i < 16; ++i) {
    a[i] = Sp[i * 16 + sub];
    v[i] = (i == sub) ? 1.f : 0.f;
    if (i == sub) diag = a[i];
  }
  jacobi16_reg(a, v, diag, lane);
  float* Vc = &Vld[mloc][0];
#pragma unroll
  for (int i = 0; i < 16; ++i) Vc[sub * 17 + i] = v[i];   // column sub, row i
  lwld[mloc][sub] = __logf(fmaxf(diag, 1e-8f));
  __syncthreads();
  // logS_{r,c} = sum_j lw_j V[r][j] V[c][j];  V[i][j] = Vc[j*17+i]
  for (int idx = sub; idx < DIMV; idx += 16) {
    int rr = (int)((sqrtf(8.f * (float)idx + 1.f) - 1.f) * 0.5f);
    while ((rr + 1) * (rr + 2) / 2 <= idx) ++rr;
    while (rr * (rr + 1) / 2 > idx) --rr;
    const int ccol = idx - rr * (rr + 1) / 2;
    float acc = 0.f;
#pragma unroll
    for (int j = 0; j < 16; ++j)
      acc += lwld[mloc][j] * Vc[j * 17 + rr] * Vc[j * 17 + ccol];
    vec[(size_t)idx * NMAT + mat] = acc;
  }
}

// ---------------------------------------------------------------------------
// K2: QKV projection. X dim-major [136][16384] (coalesced float2 loads, 2
// rows/thread); W wave-uniform; out qkv [part][b*4+h][34][1024].
// ---------------------------------------------------------------------------
__global__ __launch_bounds__(256) void k2_qkv(const float* __restrict__ X, const float* __restrict__ W,
                                              const float* __restrict__ bias, float* __restrict__ Y) {
  const int r0 = blockIdx.x * 512 + threadIdx.x * 2;
  const int n0 = blockIdx.y * 17;
  float accx[17], accy[17];
#pragma unroll
  for (int c = 0; c < 17; ++c) { const float bv = bias[n0 + c]; accx[c] = bv; accy[c] = bv; }
  for (int k = 0; k < DIMV; ++k) {
    const float2 xv = *(const float2*)&X[(size_t)k * NMAT + r0];
#pragma unroll
    for (int c = 0; c < 17; ++c) {
      const float wv = W[(size_t)(n0 + c) * DIMV + k];
      accx[c] = fmaf(wv, xv.x, accx[c]);
      accy[c] = fmaf(wv, xv.y, accy[c]);
    }
  }
  const int b = r0 >> 10, lrow = r0 & 1023;
#pragma unroll
  for (int c = 0; c < 17; ++c) {
    const int n = n0 + c;
    const int p = n / DIMV, rr = n - p * DIMV;
    const int hh = rr / HD, dd = rr - hh * HD;
    *(float2*)&Y[(((size_t)(p * 64 + b * NH + hh)) * HD + dd) * L_SZ + lrow] =
        make_float2(accx[c], accy[c]);
  }
}

// ---------------------------------------------------------------------------
// K3: flash attention via split-bf16x3 MFMA (32x32x16).
// QKV dim-major [part][bh][dim][row]; output attn DIM-MAJOR [136][16384].
// ---------------------------------------------------------------------------
__global__ __launch_bounds__(256) void k3_attn(const float* __restrict__ QKV, float* __restrict__ Oout) {
  __shared__ __align__(16) uint32_t Kh[6 * 32 * 4], Km[6 * 32 * 4], Kl[6 * 32 * 4];
  __shared__ __align__(16) uint16_t VTh[4 * 64 * 8], VTm[4 * 64 * 8], VTl[4 * 64 * 8];
  const int tid = threadIdx.x;
  const int lane = tid & 63;
  const int w = tid >> 6;
  const int bh = blockIdx.x;
  const int head = bh & 3;
  const int b = bh >> 2;
  const int qrl = lane & 31;
  const int hh = lane >> 5;
  const int row = blockIdx.y * 128 + w * 32 + qrl;
  const float* __restrict__ Qp = QKV + ((size_t)(0 * 64 + bh)) * HD * L_SZ;
  const float* __restrict__ Kp = QKV + ((size_t)(1 * 64 + bh)) * HD * L_SZ;
  const float* __restrict__ Vp = QKV + ((size_t)(2 * 64 + bh)) * HD * L_SZ;
  const float scale = 0.1714985851425088f;  // 1/sqrt(34)

  for (int i = tid; i < 6 * 32 * 4; i += 256) { Kh[i] = 0; Km[i] = 0; Kl[i] = 0; }
  for (int i = tid; i < 4 * 64 * 8; i += 256) { VTh[i] = 0; VTm[i] = 0; VTl[i] = 0; }

  F8 qfh[3], qfm[3], qfl[3];
#pragma unroll
  for (int c = 0; c < 3; ++c) {
#pragma unroll
    for (int e2 = 0; e2 < 4; ++e2) {
      const int kd = c * 16 + hh * 8 + 2 * e2;
      float x = 0.f, y = 0.f;
      if (kd < HD) {
        x = Qp[(size_t)kd * L_SZ + row] * scale;
        y = Qp[(size_t)(kd + 1) * L_SZ + row] * scale;
      }
      S3 sx = split3(x), sy = split3(y);
      qfh[c].u[e2] = pkb(sx.h, sy.h);
      qfm[c].u[e2] = pkb(sx.m, sy.m);
      qfl[c].u[e2] = pkb(sx.l, sy.l);
    }
  }

  f32x16 o0, o1;
#pragma unroll
  for (int i = 0; i < 16; ++i) { o0[i] = 0.f; o1[i] = 0.f; }
  float mrun = -3.0e38f, lsum = 0.f;

  for (int t = 0; t < 32; ++t) {
    __syncthreads();
    for (int u = tid; u < 1088; u += 256) {
      const bool isK = u < 544;
      const int e = isK ? u : u - 544;
      const int key = e & 31;
      const int j = e >> 5;
      const float* __restrict__ P = isK ? Kp : Vp;
      const size_t base = (size_t)(t * 32 + key);
      const float x = P[(size_t)(2 * j) * L_SZ + base];
      const float y = P[(size_t)(2 * j + 1) * L_SZ + base];
      const S3 sx = split3(x), sy = split3(y);
      if (isK) {
        const int di = ((j >> 2) * 32 + key) * 4 + (j & 3);
        Kh[di] = pkb(sx.h, sy.h); Km[di] = pkb(sx.m, sy.m); Kl[di] = pkb(sx.l, sy.l);
      } else {
        const int b0 = ((key >> 3) * 64 + 2 * j) * 8 + (key & 7);
        VTh[b0] = (uint16_t)(sx.h >> 16); VTm[b0] = (uint16_t)(sx.m >> 16); VTl[b0] = (uint16_t)(sx.l >> 16);
        VTh[b0 + 8] = (uint16_t)(sy.h >> 16); VTm[b0 + 8] = (uint16_t)(sy.m >> 16); VTl[b0 + 8] = (uint16_t)(sy.l >> 16);
      }
    }
    __syncthreads();

    f32x16 s;
#pragma unroll
    for (int i = 0; i < 16; ++i) s[i] = 0.f;
#pragma unroll
    for (int c = 0; c < 3; ++c) {
      F8 ah, am, al;
      const int kidx = ((c * 2 + hh) * 32 + qrl) * 4;
      ah.s = *(const short8*)&Kh[kidx];
      am.s = *(const short8*)&Km[kidx];
      al.s = *(const short8*)&Kl[kidx];
      s = __builtin_amdgcn_mfma_f32_32x32x16_bf16(ah.s, qfh[c].s, s, 0, 0, 0);
      s = __builtin_amdgcn_mfma_f32_32x32x16_bf16(ah.s, qfm[c].s, s, 0, 0, 0);
      s = __builtin_amdgcn_mfma_f32_32x32x16_bf16(am.s, qfh[c].s, s, 0, 0, 0);
      s = __builtin_amdgcn_mfma_f32_32x32x16_bf16(ah.s, qfl[c].s, s, 0, 0, 0);
      s = __builtin_amdgcn_mfma_f32_32x32x16_bf16(am.s, qfm[c].s, s, 0, 0, 0);
      s = __builtin_amdgcn_mfma_f32_32x32x16_bf16(al.s, qfh[c].s, s, 0, 0, 0);
    }

    float mymax = s[0];
#pragma unroll
    for (int e = 1; e < 16; ++e) mymax = fmaxf(mymax, s[e]);
    const float pmax = fmaxf(mymax, __shfl_xor(mymax, 32));
    const float mn = fmaxf(mrun, pmax);
    const float corr = __expf(mrun - mn);
    mrun = mn;
    float p[16]; float ps = 0.f;
#pragma unroll
    for (int e = 0; e < 16; ++e) { p[e] = __expf(s[e] - mn); ps += p[e]; }
    ps += __shfl_xor(ps, 32);
    lsum = lsum * corr + ps;
    o0 *= corr; o1 *= corr;

    uint32_t uo[3][8], po[3][8];
#pragma unroll
    for (int g = 0; g < 8; ++g) {
      const S3 s0 = split3(p[2 * g]), s1 = split3(p[2 * g + 1]);
      uo[0][g] = pkb(s0.h, s1.h); uo[1][g] = pkb(s0.m, s1.m); uo[2][g] = pkb(s0.l, s1.l);
    }
#pragma unroll
    for (int sp = 0; sp < 3; ++sp)
#pragma unroll
      for (int g = 0; g < 8; ++g) po[sp][g] = (uint32_t)__shfl_xor((int)uo[sp][g], 32);
    F8 pf[3][2];
#pragma unroll
    for (int sp = 0; sp < 3; ++sp) {
      pf[sp][0].u[0] = hh ? po[sp][2] : uo[sp][0];
      pf[sp][0].u[1] = hh ? po[sp][3] : uo[sp][1];
      pf[sp][0].u[2] = hh ? uo[sp][2] : po[sp][0];
      pf[sp][0].u[3] = hh ? uo[sp][3] : po[sp][1];
      pf[sp][1].u[0] = hh ? po[sp][6] : uo[sp][4];
      pf[sp][1].u[1] = hh ? po[sp][7] : uo[sp][5];
      pf[sp][1].u[2] = hh ? uo[sp][6] : po[sp][4];
      pf[sp][1].u[3] = hh ? uo[sp][7] : po[sp][5];
    }

#pragma unroll
    for (int dt = 0; dt < 2; ++dt) {
#pragma unroll
      for (int kc = 0; kc < 2; ++kc) {
        const int vb = ((kc * 2 + hh) * 64 + dt * 32 + qrl) * 8;
        F8 vh2, vm2, vl2;
        vh2.s = *(const short8*)&VTh[vb];
        vm2.s = *(const short8*)&VTm[vb];
        vl2.s = *(const short8*)&VTl[vb];
        f32x16 oa = dt ? o1 : o0;
        oa = __builtin_amdgcn_mfma_f32_32x32x16_bf16(vh2.s, pf[0][kc].s, oa, 0, 0, 0);
        oa = __builtin_amdgcn_mfma_f32_32x32x16_bf16(vh2.s, pf[1][kc].s, oa, 0, 0, 0);
        oa = __builtin_amdgcn_mfma_f32_32x32x16_bf16(vm2.s, pf[0][kc].s, oa, 0, 0, 0);
        oa = __builtin_amdgcn_mfma_f32_32x32x16_bf16(vh2.s, pf[2][kc].s, oa, 0, 0, 0);
        oa = __builtin_amdgcn_mfma_f32_32x32x16_bf16(vm2.s, pf[1][kc].s, oa, 0, 0, 0);
        oa = __builtin_amdgcn_mfma_f32_32x32x16_bf16(vl2.s, pf[0][kc].s, oa, 0, 0, 0);
        if (dt) o1 = oa; else o0 = oa;
      }
    }
  }

  // ---- epilogue: dim-major coalesced stores attn[head*34+d][16384] ----
  const float inv = 1.f / lsum;
  const int rowG = b * L_SZ + row;
#pragma unroll
  for (int dt = 0; dt < 2; ++dt) {
#pragma unroll
    for (int rq = 0; rq < 4; ++rq) {
#pragma unroll
      for (int j = 0; j < 4; ++j) {
        const int d = dt * 32 + 8 * rq + 4 * hh + j;
        if (d < HD) {
          const float val = (dt ? o1[rq * 4 + j] : o0[rq * 4 + j]) * inv;
          Oout[(size_t)(head * HD + d) * NMAT + rowG] = val;
        }
      }
    }
  }
}

// ---------------------------------------------------------------------------
// K4: out-projection + residual, all dim-major, 2 rows/thread, coalesced.
// ---------------------------------------------------------------------------
__global__ __launch_bounds__(256) void k4_outproj(const float* __restrict__ X, const float* __restrict__ W,
                                                  const float* __restrict__ bias, const float* __restrict__ resid,
                                                  float* __restrict__ Y) {
  const int r0 = blockIdx.x * 512 + threadIdx.x * 2;
  const int n0 = blockIdx.y * 17;
  float accx[17], accy[17];
#pragma unroll
  for (int c = 0; c < 17; ++c) { const float bv = bias[n0 + c]; accx[c] = bv; accy[c] = bv; }
  for (int k = 0; k < DIMV; ++k) {
    const float2 xv = *(const float2*)&X[(size_t)k * NMAT + r0];
#pragma unroll
    for (int c = 0; c < 17; ++c) {
      const float wv = W[(size_t)(n0 + c) * DIMV + k];
      accx[c] = fmaf(wv, xv.x, accx[c]);
      accy[c] = fmaf(wv, xv.y, accy[c]);
    }
  }
#pragma unroll
  for (int c = 0; c < 17; ++c) {
    const float2 rv = *(const float2*)&resid[(size_t)(n0 + c) * NMAT + r0];
    *(float2*)&Y[(size_t)(n0 + c) * NMAT + r0] = make_float2(accx[c] + rv.x, accy[c] + rv.y);
  }
}

// ---------------------------------------------------------------------------
// K5: rebuild symmetric matrix from vec_out (dim-major), exp_eig, write
// 16x16 output.
// ---------------------------------------------------------------------------
__global__ __launch_bounds__(256) void k5_expm(const float* __restrict__ vecOut, float* __restrict__ out) {
  __shared__ float Vld[16][272];   // V column-major
  __shared__ float eld[16][16];
  const int tid = threadIdx.x;
  const int lane = tid & 63;
  const int mloc = tid >> 4;
  const int sub = tid & 15;
  const int mat = blockIdx.x * 16 + mloc;
  float a[16], v[16], diag = 0.f;
#pragma unroll
  for (int i = 0; i < 16; ++i) {
    const int rr = i > sub ? i : sub;
    const int cc = i + sub - rr;
    a[i] = vecOut[(size_t)(rr * (rr + 1) / 2 + cc) * NMAT + mat];
    v[i] = (i == sub) ? 1.f : 0.f;
    if (i == sub) diag = a[i];
  }
  jacobi16_reg(a, v, diag, lane);
  float* Vc = &Vld[mloc][0];
#pragma unroll
  for (int i = 0; i < 16; ++i) Vc[sub * 17 + i] = v[i];   // column sub
  eld[mloc][sub] = __expf(diag);
  __syncthreads();
  // O[i][j] = sum_m e_m V[i][m] V[j][m]; this thread computes column j=sub
  float u[16];
#pragma unroll
  for (int j = 0; j < 16; ++j) u[j] = eld[mloc][j] * Vc[j * 17 + sub];
#pragma unroll
  for (int i = 0; i < 16; ++i) {
    float acc = 0.f;
#pragma unroll
    for (int j = 0; j < 16; ++j) acc = fmaf(u[j], Vc[j * 17 + i], acc);
    out[(size_t)mat * 256 + i * 16 + sub] = acc;
  }
}

// ---------------------------------------------------------------------------
extern "C" void kernel_launch(void* const* d_in, const int* in_sizes, int n_in,
                              void* d_out, int out_size, void* d_ws, size_t ws_size,
                              hipStream_t stream) {
  const float* S     = (const float*)d_in[0];
  const float* in_w  = (const float*)d_in[1];
  const float* in_b  = (const float*)d_in[2];
  const float* out_w = (const float*)d_in[3];
  const float* out_b = (const float*)d_in[4];
  float* out = (float*)d_out;
  float* ws = (float*)d_ws;
  // workspace (f32), activations dim-major:
  // vec_in[136][16384] | qkv[3][64][34][1024] | attn[136][16384] | vec_out[136][16384]
  float* vec_in  = ws;
  float* qkv     = vec_in + (size_t)NMAT * DIMV;
  float* attn    = qkv    + (size_t)NMAT * QKVD;
  float* vec_out = attn   + (size_t)NMAT * DIMV;

  k1_logvec <<<dim3(NMAT / 16),      dim3(256), 0, stream>>>(S, vec_in);
  k2_qkv    <<<dim3(NMAT / 512, 24), dim3(256), 0, stream>>>(vec_in, in_w, in_b, qkv);
  k3_attn   <<<dim3(64, 8),          dim3(256), 0, stream>>>(qkv, attn);
  k4_outproj<<<dim3(NMAT / 512, 8),  dim3(256), 0, stream>>>(attn, out_w, out_b, vec_in, vec_out);
  k5_expm   <<<dim3(NMAT / 16),      dim3(256), 0, stream>>>(vec_out, out);
}

// Round 13
// 515.950 us; speedup vs baseline: 3.7306x; 1.2345x over previous
//
#include <hip/hip_runtime.h>
#include <math.h>

#define B_SZ 16
#define L_SZ 1024
#define NMAT (B_SZ * L_SZ)   // 16384
#define DIMV 136
#define QKVD 408
#define HD 34
#define NH 4
#define NSWEEP 5

typedef __attribute__((ext_vector_type(8))) short short8;
typedef __attribute__((ext_vector_type(16))) float f32x16;
union F8 { short8 s; uint32_t u[4]; };

struct S3 { uint32_t h, m, l; };
// 3-way truncation split of f32 into bf16 parts (stored as f32 with low16=0).
__device__ __forceinline__ S3 split3(float x) {
  S3 r;
  uint32_t xb = __float_as_uint(x);
  r.h = xb & 0xffff0000u;
  float rr = x - __uint_as_float(r.h);
  r.m = __float_as_uint(rr) & 0xffff0000u;
  float r2 = rr - __uint_as_float(r.m);
  r.l = __float_as_uint(r2) & 0xffff0000u;
  return r;
}
__device__ __forceinline__ uint32_t pkb(uint32_t a, uint32_t b) { return (a >> 16) | b; }

// ---------------------------------------------------------------------------
// sel16: extract a[j] for runtime j via cndmask tree
// ---------------------------------------------------------------------------
__device__ __forceinline__ float sel16(const float a[16], int j) {
  float p0 = (j & 1) ? a[1] : a[0];
  float p1 = (j & 1) ? a[3] : a[2];
  float p2 = (j & 1) ? a[5] : a[4];
  float p3 = (j & 1) ? a[7] : a[6];
  float p4 = (j & 1) ? a[9] : a[8];
  float p5 = (j & 1) ? a[11] : a[10];
  float p6 = (j & 1) ? a[13] : a[12];
  float p7 = (j & 1) ? a[15] : a[14];
  float q0 = (j & 2) ? p1 : p0;
  float q1 = (j & 2) ? p3 : p2;
  float q2 = (j & 2) ? p5 : p4;
  float q3 = (j & 2) ? p7 : p6;
  float r0 = (j & 4) ? q1 : q0;
  float r1 = (j & 4) ? q3 : q2;
  return (j & 8) ? r1 : r0;
}

// ---------------------------------------------------------------------------
// Register+shuffle parallel cyclic Jacobi (16x16 per 16-lane group).
// R6/R11-measured form (209us, VGPR 88). Used by k1 only (log needs eigh).
// ---------------------------------------------------------------------------
__device__ __forceinline__ void jacobi16_reg(float a[16], float v[16], float& diag,
                                             const int lane) {
  const int sub = lane & 15;
  const int gbase = lane & 48;
  for (int sweep = 0; sweep < NSWEEP; ++sweep) {
#pragma unroll
    for (int r = 0; r < 15; ++r) {
      int partner;
      if (sub == 15) partner = r;
      else {
        int d = sub - r; if (d < 0) d += 15;
        if (d == 0) partner = 15;
        else if (d <= 7) { partner = r - d; if (partner < 0) partner += 15; }
        else { partner = r + 15 - d; if (partner >= 15) partner -= 15; }
      }
      const int plane = gbase | partner;
      float oa[16], ov[16];
#pragma unroll
      for (int i = 0; i < 16; ++i) oa[i] = __shfl(a[i], plane);
#pragma unroll
      for (int i = 0; i < 16; ++i) ov[i] = __shfl(v[i], plane);
      const float diag_o = __shfl(diag, plane);
      const bool amP = sub < partner;
      const float app = amP ? diag : diag_o;
      const float aqq = amP ? diag_o : diag;
      const float apq_loc = sel16(a, partner);
      const int pl = gbase | (amP ? sub : partner);
      const float apq = __shfl(apq_loc, pl);
      float c, s, t;
      {
        float theta = (aqq - app) / (2.f * apq);
        float tt = 1.f / (fabsf(theta) + sqrtf(fmaf(theta, theta, 1.f)));
        tt = (theta < 0.f) ? -tt : tt;
        t = (fabsf(apq) < 1e-30f) ? 0.f : tt;
        c = rsqrtf(fmaf(t, t, 1.f));
        s = t * c;
      }
      const float sgn = amP ? -s : s;
#pragma unroll
      for (int i = 0; i < 16; ++i) {
        a[i] = fmaf(sgn, oa[i], c * a[i]);
        v[i] = fmaf(sgn, ov[i], c * v[i]);
      }
      const float cc = c * c, ss2 = s * s, cs2 = 2.f * c * s;
      const float dp = fmaf(cc, app, fmaf(ss2, aqq, -cs2 * apq));
      const float dq = fmaf(ss2, app, fmaf(cc, aqq, cs2 * apq));
      diag = amP ? dp : dq;
#pragma unroll
      for (int k = 0; k < 8; ++k) {
        const int owner = (k == 0) ? r : (r + k) % 15;
        const float tk = __shfl(t, gbase | owner);
        const float ck = rsqrtf(fmaf(tk, tk, 1.f));
        const float sk = tk * ck;
        int pk, qk;
        if (k == 0) { pk = r; qk = 15; }
        else {
          const int u = (r + k) % 15, w = (r + 15 - k) % 15;
          pk = u < w ? u : w; qk = u < w ? w : u;
        }
        float tp = a[pk], tq = a[qk];
        a[pk] = fmaf(-sk, tq, ck * tp);
        a[qk] = fmaf(sk, tp, ck * tq);
      }
    }
  }
}

// ---------------------------------------------------------------------------
// K1: log_eig(S) -> tril vector, DIM-MAJOR out: vec[136][16384]
// ---------------------------------------------------------------------------
__global__ __launch_bounds__(256) void k1_logvec(const float* __restrict__ S, float* __restrict__ vec) {
  __shared__ float Vld[16][272];   // V column-major: Vld[m][col*17 + row]
  __shared__ float lwld[16][16];
  const int tid = threadIdx.x;
  const int lane = tid & 63;
  const int mloc = tid >> 4;
  const int sub = tid & 15;
  const int mat = blockIdx.x * 16 + mloc;
  float a[16], v[16], diag = 0.f;
  const float* Sp = S + (size_t)mat * 256;
#pragma unroll
  for (int i = 0; i < 16; ++i) {
    a[i] = Sp[i * 16 + sub];
    v[i] = (i == sub) ? 1.f : 0.f;
    if (i == sub) diag = a[i];
  }
  jacobi16_reg(a, v, diag, lane);
  float* Vc = &Vld[mloc][0];
#pragma unroll
  for (int i = 0; i < 16; ++i) Vc[sub * 17 + i] = v[i];   // column sub, row i
  lwld[mloc][sub] = __logf(fmaxf(diag, 1e-8f));
  __syncthreads();
  // logS_{r,c} = sum_j lw_j V[r][j] V[c][j];  V[i][j] = Vc[j*17+i]
  for (int idx = sub; idx < DIMV; idx += 16) {
    int rr = (int)((sqrtf(8.f * (float)idx + 1.f) - 1.f) * 0.5f);
    while ((rr + 1) * (rr + 2) / 2 <= idx) ++rr;
    while (rr * (rr + 1) / 2 > idx) --rr;
    const int ccol = idx - rr * (rr + 1) / 2;
    float acc = 0.f;
#pragma unroll
    for (int j = 0; j < 16; ++j)
      acc += lwld[mloc][j] * Vc[j * 17 + rr] * Vc[j * 17 + ccol];
    vec[(size_t)idx * NMAT + mat] = acc;
  }
}

// ---------------------------------------------------------------------------
// K2: QKV projection. X dim-major [136][16384] (coalesced float2 loads, 2
// rows/thread); W wave-uniform; out qkv [part][b*4+h][34][1024].
// ---------------------------------------------------------------------------
__global__ __launch_bounds__(256) void k2_qkv(const float* __restrict__ X, const float* __restrict__ W,
                                              const float* __restrict__ bias, float* __restrict__ Y) {
  const int r0 = blockIdx.x * 512 + threadIdx.x * 2;
  const int n0 = blockIdx.y * 17;
  float accx[17], accy[17];
#pragma unroll
  for (int c = 0; c < 17; ++c) { const float bv = bias[n0 + c]; accx[c] = bv; accy[c] = bv; }
  for (int k = 0; k < DIMV; ++k) {
    const float2 xv = *(const float2*)&X[(size_t)k * NMAT + r0];
#pragma unroll
    for (int c = 0; c < 17; ++c) {
      const float wv = W[(size_t)(n0 + c) * DIMV + k];
      accx[c] = fmaf(wv, xv.x, accx[c]);
      accy[c] = fmaf(wv, xv.y, accy[c]);
    }
  }
  const int b = r0 >> 10, lrow = r0 & 1023;
#pragma unroll
  for (int c = 0; c < 17; ++c) {
    const int n = n0 + c;
    const int p = n / DIMV, rr = n - p * DIMV;
    const int hh = rr / HD, dd = rr - hh * HD;
    *(float2*)&Y[(((size_t)(p * 64 + b * NH + hh)) * HD + dd) * L_SZ + lrow] =
        make_float2(accx[c], accy[c]);
  }
}

// ---------------------------------------------------------------------------
// K3: flash attention via split-bf16x3 MFMA (32x32x16).
// QKV dim-major [part][bh][dim][row]; output attn DIM-MAJOR [136][16384].
// ---------------------------------------------------------------------------
__global__ __launch_bounds__(256) void k3_attn(const float* __restrict__ QKV, float* __restrict__ Oout) {
  __shared__ __align__(16) uint32_t Kh[6 * 32 * 4], Km[6 * 32 * 4], Kl[6 * 32 * 4];
  __shared__ __align__(16) uint16_t VTh[4 * 64 * 8], VTm[4 * 64 * 8], VTl[4 * 64 * 8];
  const int tid = threadIdx.x;
  const int lane = tid & 63;
  const int w = tid >> 6;
  const int bh = blockIdx.x;
  const int head = bh & 3;
  const int b = bh >> 2;
  const int qrl = lane & 31;
  const int hh = lane >> 5;
  const int row = blockIdx.y * 128 + w * 32 + qrl;
  const float* __restrict__ Qp = QKV + ((size_t)(0 * 64 + bh)) * HD * L_SZ;
  const float* __restrict__ Kp = QKV + ((size_t)(1 * 64 + bh)) * HD * L_SZ;
  const float* __restrict__ Vp = QKV + ((size_t)(2 * 64 + bh)) * HD * L_SZ;
  const float scale = 0.1714985851425088f;  // 1/sqrt(34)

  for (int i = tid; i < 6 * 32 * 4; i += 256) { Kh[i] = 0; Km[i] = 0; Kl[i] = 0; }
  for (int i = tid; i < 4 * 64 * 8; i += 256) { VTh[i] = 0; VTm[i] = 0; VTl[i] = 0; }

  F8 qfh[3], qfm[3], qfl[3];
#pragma unroll
  for (int c = 0; c < 3; ++c) {
#pragma unroll
    for (int e2 = 0; e2 < 4; ++e2) {
      const int kd = c * 16 + hh * 8 + 2 * e2;
      float x = 0.f, y = 0.f;
      if (kd < HD) {
        x = Qp[(size_t)kd * L_SZ + row] * scale;
        y = Qp[(size_t)(kd + 1) * L_SZ + row] * scale;
      }
      S3 sx = split3(x), sy = split3(y);
      qfh[c].u[e2] = pkb(sx.h, sy.h);
      qfm[c].u[e2] = pkb(sx.m, sy.m);
      qfl[c].u[e2] = pkb(sx.l, sy.l);
    }
  }

  f32x16 o0, o1;
#pragma unroll
  for (int i = 0; i < 16; ++i) { o0[i] = 0.f; o1[i] = 0.f; }
  float mrun = -3.0e38f, lsum = 0.f;

  for (int t = 0; t < 32; ++t) {
    __syncthreads();
    for (int u = tid; u < 1088; u += 256) {
      const bool isK = u < 544;
      const int e = isK ? u : u - 544;
      const int key = e & 31;
      const int j = e >> 5;
      const float* __restrict__ P = isK ? Kp : Vp;
      const size_t base = (size_t)(t * 32 + key);
      const float x = P[(size_t)(2 * j) * L_SZ + base];
      const float y = P[(size_t)(2 * j + 1) * L_SZ + base];
      const S3 sx = split3(x), sy = split3(y);
      if (isK) {
        const int di = ((j >> 2) * 32 + key) * 4 + (j & 3);
        Kh[di] = pkb(sx.h, sy.h); Km[di] = pkb(sx.m, sy.m); Kl[di] = pkb(sx.l, sy.l);
      } else {
        const int b0 = ((key >> 3) * 64 + 2 * j) * 8 + (key & 7);
        VTh[b0] = (uint16_t)(sx.h >> 16); VTm[b0] = (uint16_t)(sx.m >> 16); VTl[b0] = (uint16_t)(sx.l >> 16);
        VTh[b0 + 8] = (uint16_t)(sy.h >> 16); VTm[b0 + 8] = (uint16_t)(sy.m >> 16); VTl[b0 + 8] = (uint16_t)(sy.l >> 16);
      }
    }
    __syncthreads();

    f32x16 s;
#pragma unroll
    for (int i = 0; i < 16; ++i) s[i] = 0.f;
#pragma unroll
    for (int c = 0; c < 3; ++c) {
      F8 ah, am, al;
      const int kidx = ((c * 2 + hh) * 32 + qrl) * 4;
      ah.s = *(const short8*)&Kh[kidx];
      am.s = *(const short8*)&Km[kidx];
      al.s = *(const short8*)&Kl[kidx];
      s = __builtin_amdgcn_mfma_f32_32x32x16_bf16(ah.s, qfh[c].s, s, 0, 0, 0);
      s = __builtin_amdgcn_mfma_f32_32x32x16_bf16(ah.s, qfm[c].s, s, 0, 0, 0);
      s = __builtin_amdgcn_mfma_f32_32x32x16_bf16(am.s, qfh[c].s, s, 0, 0, 0);
      s = __builtin_amdgcn_mfma_f32_32x32x16_bf16(ah.s, qfl[c].s, s, 0, 0, 0);
      s = __builtin_amdgcn_mfma_f32_32x32x16_bf16(am.s, qfm[c].s, s, 0, 0, 0);
      s = __builtin_amdgcn_mfma_f32_32x32x16_bf16(al.s, qfh[c].s, s, 0, 0, 0);
    }

    float mymax = s[0];
#pragma unroll
    for (int e = 1; e < 16; ++e) mymax = fmaxf(mymax, s[e]);
    const float pmax = fmaxf(mymax, __shfl_xor(mymax, 32));
    const float mn = fmaxf(mrun, pmax);
    const float corr = __expf(mrun - mn);
    mrun = mn;
    float p[16]; float ps = 0.f;
#pragma unroll
    for (int e = 0; e < 16; ++e) { p[e] = __expf(s[e] - mn); ps += p[e]; }
    ps += __shfl_xor(ps, 32);
    lsum = lsum * corr + ps;
    o0 *= corr; o1 *= corr;

    uint32_t uo[3][8], po[3][8];
#pragma unroll
    for (int g = 0; g < 8; ++g) {
      const S3 s0 = split3(p[2 * g]), s1 = split3(p[2 * g + 1]);
      uo[0][g] = pkb(s0.h, s1.h); uo[1][g] = pkb(s0.m, s1.m); uo[2][g] = pkb(s0.l, s1.l);
    }
#pragma unroll
    for (int sp = 0; sp < 3; ++sp)
#pragma unroll
      for (int g = 0; g < 8; ++g) po[sp][g] = (uint32_t)__shfl_xor((int)uo[sp][g], 32);
    F8 pf[3][2];
#pragma unroll
    for (int sp = 0; sp < 3; ++sp) {
      pf[sp][0].u[0] = hh ? po[sp][2] : uo[sp][0];
      pf[sp][0].u[1] = hh ? po[sp][3] : uo[sp][1];
      pf[sp][0].u[2] = hh ? uo[sp][2] : po[sp][0];
      pf[sp][0].u[3] = hh ? uo[sp][3] : po[sp][1];
      pf[sp][1].u[0] = hh ? po[sp][6] : uo[sp][4];
      pf[sp][1].u[1] = hh ? po[sp][7] : uo[sp][5];
      pf[sp][1].u[2] = hh ? uo[sp][6] : po[sp][4];
      pf[sp][1].u[3] = hh ? uo[sp][7] : po[sp][5];
    }

#pragma unroll
    for (int dt = 0; dt < 2; ++dt) {
#pragma unroll
      for (int kc = 0; kc < 2; ++kc) {
        const int vb = ((kc * 2 + hh) * 64 + dt * 32 + qrl) * 8;
        F8 vh2, vm2, vl2;
        vh2.s = *(const short8*)&VTh[vb];
        vm2.s = *(const short8*)&VTm[vb];
        vl2.s = *(const short8*)&VTl[vb];
        f32x16 oa = dt ? o1 : o0;
        oa = __builtin_amdgcn_mfma_f32_32x32x16_bf16(vh2.s, pf[0][kc].s, oa, 0, 0, 0);
        oa = __builtin_amdgcn_mfma_f32_32x32x16_bf16(vh2.s, pf[1][kc].s, oa, 0, 0, 0);
        oa = __builtin_amdgcn_mfma_f32_32x32x16_bf16(vm2.s, pf[0][kc].s, oa, 0, 0, 0);
        oa = __builtin_amdgcn_mfma_f32_32x32x16_bf16(vh2.s, pf[2][kc].s, oa, 0, 0, 0);
        oa = __builtin_amdgcn_mfma_f32_32x32x16_bf16(vm2.s, pf[1][kc].s, oa, 0, 0, 0);
        oa = __builtin_amdgcn_mfma_f32_32x32x16_bf16(vl2.s, pf[0][kc].s, oa, 0, 0, 0);
        if (dt) o1 = oa; else o0 = oa;
      }
    }
  }

  // ---- epilogue: dim-major coalesced stores attn[head*34+d][16384] ----
  const float inv = 1.f / lsum;
  const int rowG = b * L_SZ + row;
#pragma unroll
  for (int dt = 0; dt < 2; ++dt) {
#pragma unroll
    for (int rq = 0; rq < 4; ++rq) {
#pragma unroll
      for (int j = 0; j < 4; ++j) {
        const int d = dt * 32 + 8 * rq + 4 * hh + j;
        if (d < HD) {
          const float val = (dt ? o1[rq * 4 + j] : o0[rq * 4 + j]) * inv;
          Oout[(size_t)(head * HD + d) * NMAT + rowG] = val;
        }
      }
    }
  }
}

// ---------------------------------------------------------------------------
// K4: out-projection + residual, all dim-major, 2 rows/thread, coalesced.
// ---------------------------------------------------------------------------
__global__ __launch_bounds__(256) void k4_outproj(const float* __restrict__ X, const float* __restrict__ W,
                                                  const float* __restrict__ bias, const float* __restrict__ resid,
                                                  float* __restrict__ Y) {
  const int r0 = blockIdx.x * 512 + threadIdx.x * 2;
  const int n0 = blockIdx.y * 17;
  float accx[17], accy[17];
#pragma unroll
  for (int c = 0; c < 17; ++c) { const float bv = bias[n0 + c]; accx[c] = bv; accy[c] = bv; }
  for (int k = 0; k < DIMV; ++k) {
    const float2 xv = *(const float2*)&X[(size_t)k * NMAT + r0];
#pragma unroll
    for (int c = 0; c < 17; ++c) {
      const float wv = W[(size_t)(n0 + c) * DIMV + k];
      accx[c] = fmaf(wv, xv.x, accx[c]);
      accy[c] = fmaf(wv, xv.y, accy[c]);
    }
  }
#pragma unroll
  for (int c = 0; c < 17; ++c) {
    const float2 rv = *(const float2*)&resid[(size_t)(n0 + c) * NMAT + r0];
    *(float2*)&Y[(size_t)(n0 + c) * NMAT + r0] = make_float2(accx[c] + rv.x, accy[c] + rv.y);
  }
}

// ---------------------------------------------------------------------------
// K5: expm via scaling-and-squaring Taylor (degree 6) on bf16x3 MFMA.
// One wave = 2 matrices packed block-diagonally in 32x32x16 MFMAs.
// Symmetric operands => rows == cols => one fragment serves A and B.
// Fragment form: F[e] = X[8h+e][xp] (h=lane>>5, xp=(lane&31)&15).
// C layout (col=lane&31, row=(q&3)+8(q>>2)+4h): useful regs q in
// {8m..8m+7} for matrix m=(lane&31)>>4; repack via shfl_xor(32).
// ---------------------------------------------------------------------------
__device__ __forceinline__ void frag_from_acc(const f32x16& acc, bool hiM, int h, float F[8]) {
  float uq[8], rq[8];
#pragma unroll
  for (int j = 0; j < 8; ++j) uq[j] = hiM ? acc[8 + j] : acc[j];
#pragma unroll
  for (int j = 0; j < 8; ++j) rq[j] = __shfl_xor(uq[j], 32);
  F[0] = h ? rq[4] : uq[0];
  F[1] = h ? rq[5] : uq[1];
  F[2] = h ? rq[6] : uq[2];
  F[3] = h ? rq[7] : uq[3];
  F[4] = h ? uq[4] : rq[0];
  F[5] = h ? uq[5] : rq[1];
  F[6] = h ? uq[6] : rq[2];
  F[7] = h ? uq[7] : rq[3];
}

__device__ __forceinline__ void split_frag(const float F[8], F8& Xh, F8& Xm, F8& Xl) {
#pragma unroll
  for (int e2 = 0; e2 < 4; ++e2) {
    const S3 a = split3(F[2 * e2]), b = split3(F[2 * e2 + 1]);
    Xh.u[e2] = pkb(a.h, b.h);
    Xm.u[e2] = pkb(a.m, b.m);
    Xl.u[e2] = pkb(a.l, b.l);
  }
}

__device__ __forceinline__ f32x16 mm6(const F8& Ah, const F8& Am, const F8& Al,
                                      const F8& Bh, const F8& Bm, const F8& Bl) {
  f32x16 acc;
#pragma unroll
  for (int i = 0; i < 16; ++i) acc[i] = 0.f;
  acc = __builtin_amdgcn_mfma_f32_32x32x16_bf16(Ah.s, Bh.s, acc, 0, 0, 0);
  acc = __builtin_amdgcn_mfma_f32_32x32x16_bf16(Ah.s, Bm.s, acc, 0, 0, 0);
  acc = __builtin_amdgcn_mfma_f32_32x32x16_bf16(Am.s, Bh.s, acc, 0, 0, 0);
  acc = __builtin_amdgcn_mfma_f32_32x32x16_bf16(Ah.s, Bl.s, acc, 0, 0, 0);
  acc = __builtin_amdgcn_mfma_f32_32x32x16_bf16(Am.s, Bm.s, acc, 0, 0, 0);
  acc = __builtin_amdgcn_mfma_f32_32x32x16_bf16(Al.s, Bh.s, acc, 0, 0, 0);
  return acc;
}

__global__ __launch_bounds__(256) void k5_expm(const float* __restrict__ vecOut, float* __restrict__ out) {
  const int tid = threadIdx.x;
  const int lane = tid & 63;
  const int wv = tid >> 6;
  const int h = lane >> 5;
  const int x = lane & 31;
  const int xp = x & 15;
  const bool hiM = (x >> 4) != 0;
  const int mat = blockIdx.x * 8 + wv * 2 + (x >> 4);

  // ---- load column xp of M (sym rebuild from tril vec, dim-major) ----
  float m[16];
  float nrm = 0.f;
#pragma unroll
  for (int i = 0; i < 16; ++i) {
    const int rr = i > xp ? i : xp;
    const int cc = i + xp - rr;
    m[i] = vecOut[(size_t)(rr * (rr + 1) / 2 + cc) * NMAT + mat];
    nrm += fabsf(m[i]);
  }
  // wave-wide max (covers both matrices -> wave-uniform s)
#pragma unroll
  for (int off = 1; off <= 32; off <<= 1) nrm = fmaxf(nrm, __shfl_xor(nrm, off));
  int ex;
  frexpf(nrm, &ex);                 // nrm <= 2^ex
  int sq = ex + 2;
  sq = sq < 0 ? 0 : (sq > 15 ? 15 : sq);   // ||B|| <= 0.25
  const float scl = __int_as_float((uint32_t)(127 - sq) << 23);  // 2^-sq

  // ---- B fragment: F[e] = B[8h+e][xp] (column slice; symmetric) ----
  float bF[8];
#pragma unroll
  for (int e = 0; e < 8; ++e) bF[e] = (h ? m[8 + e] : m[e]) * scl;
  F8 Bh, Bm, Bl;
  split_frag(bF, Bh, Bm, Bl);

  // ---- T = I + B/6 ----
  float tF[8];
#pragma unroll
  for (int e = 0; e < 8; ++e)
    tF[e] = fmaf(bF[e], 1.f / 6.f, (xp == (h ? 8 : 0) + e) ? 1.f : 0.f);
  F8 Th, Tm, Tl;
  split_frag(tF, Th, Tm, Tl);

  // ---- Horner: T = I + (B*T)/c for c = 5,4,3,2,1 ----
  const float invc[5] = {0.2f, 0.25f, 1.f / 3.f, 0.5f, 1.f};
#pragma unroll
  for (int kk = 0; kk < 5; ++kk) {
    f32x16 acc = mm6(Bh, Bm, Bl, Th, Tm, Tl);
    float F[8];
    frag_from_acc(acc, hiM, h, F);
#pragma unroll
    for (int e = 0; e < 8; ++e)
      tF[e] = fmaf(F[e], invc[kk], (xp == (h ? 8 : 0) + e) ? 1.f : 0.f);
    split_frag(tF, Th, Tm, Tl);
  }

  // ---- sq squarings: T = T*T ----
  for (int i = 0; i < sq; ++i) {
    f32x16 acc = mm6(Th, Tm, Tl, Th, Tm, Tl);
    frag_from_acc(acc, hiM, h, tF);
    split_frag(tF, Th, Tm, Tl);
  }

  // ---- store: tF[e] = E[8h+e][xp] -> out[mat][8h+e][xp] ----
  float* op = out + (size_t)mat * 256 + xp;
#pragma unroll
  for (int e = 0; e < 8; ++e) op[(h * 8 + e) * 16] = tF[e];
}

// ---------------------------------------------------------------------------
extern "C" void kernel_launch(void* const* d_in, const int* in_sizes, int n_in,
                              void* d_out, int out_size, void* d_ws, size_t ws_size,
                              hipStream_t stream) {
  const float* S     = (const float*)d_in[0];
  const float* in_w  = (const float*)d_in[1];
  const float* in_b  = (const float*)d_in[2];
  const float* out_w = (const float*)d_in[3];
  const float* out_b = (const float*)d_in[4];
  float* out = (float*)d_out;
  float* ws = (float*)d_ws;
  // workspace (f32), activations dim-major:
  // vec_in[136][16384] | qkv[3][64][34][1024] | attn[136][16384] | vec_out[136][16384]
  float* vec_in  = ws;
  float* qkv     = vec_in + (size_t)NMAT * DIMV;
  float* attn    = qkv    + (size_t)NMAT * QKVD;
  float* vec_out = attn   + (size_t)NMAT * DIMV;

  k1_logvec <<<dim3(NMAT / 16),      dim3(256), 0, stream>>>(S, vec_in);
  k2_qkv    <<<dim3(NMAT / 512, 24), dim3(256), 0, stream>>>(vec_in, in_w, in_b, qkv);
  k3_attn   <<<dim3(64, 8),          dim3(256), 0, stream>>>(qkv, attn);
  k4_outproj<<<dim3(NMAT / 512, 8),  dim3(256), 0, stream>>>(attn, out_w, out_b, vec_in, vec_out);
  k5_expm   <<<dim3(NMAT / 8),       dim3(256), 0, stream>>>(vec_out, out);
}